// Round 1
// baseline (353.775 us; speedup 1.0000x reference)
//
#include <hip/hip_runtime.h>
#include <hip/hip_bf16.h>

#define S_LEN 2048
#define BATCH 2
#define EDIM 1024
#define NHEAD 16
#define DHEAD 64
#define HIDDEN 512
#define SIGD 64
#define KEEP 12           // NUM_HEADS - INACTIVE

typedef __attribute__((ext_vector_type(8))) short bf16x8;
typedef __attribute__((ext_vector_type(4))) float f32x4;

static __device__ __forceinline__ float bf2f(short s) {
  unsigned int u = ((unsigned int)(unsigned short)s) << 16;
  float f; __builtin_memcpy(&f, &u, 4); return f;
}
static __device__ __forceinline__ short f2bf(float f) {
  unsigned int u; __builtin_memcpy(&u, &f, 4);
  u += 0x7fffu + ((u >> 16) & 1u);   // round-to-nearest-even
  return (short)(u >> 16);
}

#if __has_builtin(__builtin_amdgcn_exp2f)
static __device__ __forceinline__ float fexp2(float x) { return __builtin_amdgcn_exp2f(x); }
#else
static __device__ __forceinline__ float fexp2(float x) { return exp2f(x); }
#endif

// async global->LDS, 16B per lane. LDS dest is wave-uniform base + lane*16.
static __device__ __forceinline__ void gl_lds16(const short* g, short* l) {
  __builtin_amdgcn_global_load_lds(
      (const __attribute__((address_space(1))) unsigned int*)g,
      (__attribute__((address_space(3))) unsigned int*)l, 16, 0, 0);
}

// DPP all-reduce across the 16 lanes of a DPP row (= our quad group).
template<int CTRL>
static __device__ __forceinline__ float dpp_movf(float x) {
  return __builtin_bit_cast(float, __builtin_amdgcn_update_dpp(
      0, __builtin_bit_cast(int, x), CTRL, 0xF, 0xF, true));
}
static __device__ __forceinline__ float row_max16(float v) {
  v = fmaxf(v, dpp_movf<0x128>(v));   // row_ror:8
  v = fmaxf(v, dpp_movf<0x124>(v));   // row_ror:4
  v = fmaxf(v, dpp_movf<0x122>(v));   // row_ror:2
  v = fmaxf(v, dpp_movf<0x121>(v));   // row_ror:1
  return v;
}
static __device__ __forceinline__ float row_sum16(float v) {
  v += dpp_movf<0x128>(v);
  v += dpp_movf<0x124>(v);
  v += dpp_movf<0x122>(v);
  v += dpp_movf<0x121>(v);
  return v;
}

// ---------------- kernel 1: ALL dtype conversions in one launch ----------------
// [0,4096): query hi/lo split. [4096,4608): inf1_w hi/lo split.
// [4608,5632) Wq, [5632,6656) Wk, [6656,7680) Wv, [7680,8704) Wo (plain bf16).
__global__ __launch_bounds__(256) void cvt_all(
    const float* __restrict__ query, const float* __restrict__ inf1_w,
    const float* __restrict__ qw, const float* __restrict__ kw,
    const float* __restrict__ vw, const float* __restrict__ ow,
    short* __restrict__ qh, short* __restrict__ ql,
    short* __restrict__ w1h, short* __restrict__ w1l,
    short* __restrict__ Wq, short* __restrict__ Wk,
    short* __restrict__ Wv, short* __restrict__ Wo)
{
  int blk = blockIdx.x;
  if (blk < 4608) {              // split sections
    const float* in; short *oh, *ol; int i;
    if (blk < 4096) { in = query;  oh = qh;  ol = ql;  i = (blk * 256 + threadIdx.x) * 4; }
    else            { in = inf1_w; oh = w1h; ol = w1l; i = ((blk - 4096) * 256 + threadIdx.x) * 4; }
    float4 f = *(const float4*)(in + i);
    union { short s[4]; uint2 v; } uh, ul;
    float x[4] = {f.x, f.y, f.z, f.w};
    #pragma unroll
    for (int u = 0; u < 4; ++u) {
      short h = f2bf(x[u]);
      uh.s[u] = h;
      ul.s[u] = f2bf(x[u] - bf2f(h));
    }
    *(uint2*)(oh + i) = uh.v;
    *(uint2*)(ol + i) = ul.v;
  } else {                       // plain bf16 sections (1024 blocks each)
    int t = blk - 4608;
    int mat = t >> 10, sub = t & 1023;
    const float* in = (mat == 0) ? qw : (mat == 1) ? kw : (mat == 2) ? vw : ow;
    short* out      = (mat == 0) ? Wq : (mat == 1) ? Wk : (mat == 2) ? Wv : Wo;
    int i = (sub * 256 + threadIdx.x) * 4;
    float4 f = *(const float4*)(in + i);
    union { short s[4]; uint2 v; } u;
    u.s[0] = f2bf(f.x); u.s[1] = f2bf(f.y); u.s[2] = f2bf(f.z); u.s[3] = f2bf(f.w);
    *(uint2*)(out + i) = u.v;
  }
}

// ---------------- m97-style 128x128 GEMM body (smem passed in) ----------------
template<bool F32OUT>
static __device__ __forceinline__ void gemm128_body(
    short* smem,
    const short* __restrict__ A, const short* __restrict__ B,
    const float* __restrict__ bias, void* __restrict__ outv,
    int row0, int col0, float scale)
{
  short* As = smem;              // 128*32
  short* Bs = smem + 128*32;     // 128*32
  const int tid  = threadIdx.x;
  const int wave = tid >> 6, lane = tid & 63;
  const int quad = lane >> 4, l16 = lane & 15;
  const int wr = wave >> 1, wc = wave & 1;
  const int lr = lane >> 2, lc8 = (lane & 3) * 8;

  const short* gA = A + (size_t)(row0 + wave*16 + lr) * EDIM + lc8;
  const short* gB = B + (size_t)(col0 + wave*16 + lr) * EDIM + lc8;
  short* lA = As + wave*512;
  short* lB = Bs + wave*512;

  f32x4 acc[4][4] = {};
  gl_lds16(gA, lA);  gl_lds16(gA + 64*EDIM, lA + 64*32);
  gl_lds16(gB, lB);  gl_lds16(gB + 64*EDIM, lB + 64*32);

  for (int k0 = 0; k0 < EDIM; k0 += 32) {
    __syncthreads();
    bf16x8 af[4], bfr[4];
    #pragma unroll
    for (int i = 0; i < 4; ++i)
      af[i] = *(const bf16x8*)&As[(wr*64 + i*16 + l16)*32 + quad*8];
    #pragma unroll
    for (int j = 0; j < 4; ++j)
      bfr[j] = *(const bf16x8*)&Bs[(wc*64 + j*16 + l16)*32 + quad*8];
    __syncthreads();
    if (k0 + 32 < EDIM) {
      const short* gA2 = gA + k0 + 32;
      const short* gB2 = gB + k0 + 32;
      gl_lds16(gA2, lA);  gl_lds16(gA2 + 64*EDIM, lA + 64*32);
      gl_lds16(gB2, lB);  gl_lds16(gB2 + 64*EDIM, lB + 64*32);
    }
    #pragma unroll
    for (int i = 0; i < 4; ++i)
      #pragma unroll
      for (int j = 0; j < 4; ++j)
        acc[i][j] = __builtin_amdgcn_mfma_f32_16x16x32_bf16(af[i], bfr[j], acc[i][j], 0, 0, 0);
  }
  #pragma unroll
  for (int j = 0; j < 4; ++j) {
    int col = col0 + wc*64 + j*16 + l16;
    float bv = bias[col];
    #pragma unroll
    for (int i = 0; i < 4; ++i) {
      int rowb = row0 + wr*64 + i*16 + quad*4;
      #pragma unroll
      for (int r = 0; r < 4; ++r) {
        float v = (acc[i][j][r] + bv) * scale;
        if constexpr (F32OUT) {
          ((float*)outv)[(size_t)(rowb + r) * EDIM + col] = v;
        } else {
          ((short*)outv)[(size_t)(rowb + r) * EDIM + col] = f2bf(v);
        }
      }
    }
  }
}

// t1 body: 128x64 tile, hi/lo-split (3 MFMAs, fp32-accurate), relu -> T1 fp32.
static __device__ __forceinline__ void gemm_t1_body(
    short* smem,
    const short* __restrict__ Agh, const short* __restrict__ Agl,
    const short* __restrict__ Bgh, const short* __restrict__ Bgl,
    const float* __restrict__ bias, float* __restrict__ T1,
    int row0, int col0)
{
  short* Ah = smem;              // 128*32
  short* Al = smem + 4096;      // 128*32
  short* Bh = smem + 8192;      // 64*32
  short* Bl = smem + 10240;     // 64*32
  const int tid  = threadIdx.x;
  const int wave = tid >> 6, lane = tid & 63;
  const int quad = lane >> 4, l16 = lane & 15;
  const int wr = wave >> 1, wc = wave & 1;
  const int lr = lane >> 2, lc8 = (lane & 3) * 8;

  const short* gAh = Agh + (size_t)(row0 + wave*16 + lr) * EDIM + lc8;
  const short* gAl = Agl + (size_t)(row0 + wave*16 + lr) * EDIM + lc8;
  const short* gBh = Bgh + (size_t)(col0 + wave*16 + lr) * EDIM + lc8;
  const short* gBl = Bgl + (size_t)(col0 + wave*16 + lr) * EDIM + lc8;
  short* lAh = Ah + wave*512;  short* lAl = Al + wave*512;
  short* lBh = Bh + wave*512;  short* lBl = Bl + wave*512;

  f32x4 acc[4][2] = {};
  gl_lds16(gAh, lAh);  gl_lds16(gAh + 64*EDIM, lAh + 64*32);
  gl_lds16(gAl, lAl);  gl_lds16(gAl + 64*EDIM, lAl + 64*32);
  gl_lds16(gBh, lBh);  gl_lds16(gBl, lBl);

  for (int k0 = 0; k0 < EDIM; k0 += 32) {
    __syncthreads();
    bf16x8 ah[4], al[4], bh[2], bl[2];
    #pragma unroll
    for (int i = 0; i < 4; ++i) {
      ah[i] = *(const bf16x8*)&Ah[(wr*64 + i*16 + l16)*32 + quad*8];
      al[i] = *(const bf16x8*)&Al[(wr*64 + i*16 + l16)*32 + quad*8];
    }
    #pragma unroll
    for (int j = 0; j < 2; ++j) {
      bh[j] = *(const bf16x8*)&Bh[(wc*32 + j*16 + l16)*32 + quad*8];
      bl[j] = *(const bf16x8*)&Bl[(wc*32 + j*16 + l16)*32 + quad*8];
    }
    __syncthreads();
    if (k0 + 32 < EDIM) {
      const short* p;
      p = gAh + k0 + 32;  gl_lds16(p, lAh);  gl_lds16(p + 64*EDIM, lAh + 64*32);
      p = gAl + k0 + 32;  gl_lds16(p, lAl);  gl_lds16(p + 64*EDIM, lAl + 64*32);
      gl_lds16(gBh + k0 + 32, lBh);  gl_lds16(gBl + k0 + 32, lBl);
    }
    #pragma unroll
    for (int i = 0; i < 4; ++i)
      #pragma unroll
      for (int j = 0; j < 2; ++j) {
        acc[i][j] = __builtin_amdgcn_mfma_f32_16x16x32_bf16(ah[i], bh[j], acc[i][j], 0, 0, 0);
        acc[i][j] = __builtin_amdgcn_mfma_f32_16x16x32_bf16(ah[i], bl[j], acc[i][j], 0, 0, 0);
        acc[i][j] = __builtin_amdgcn_mfma_f32_16x16x32_bf16(al[i], bh[j], acc[i][j], 0, 0, 0);
      }
  }
  #pragma unroll
  for (int j = 0; j < 2; ++j) {
    int col = col0 + wc*32 + j*16 + l16;
    float bv = bias[col];
    #pragma unroll
    for (int i = 0; i < 4; ++i) {
      int rowb = row0 + wr*64 + i*16 + quad*4;
      #pragma unroll
      for (int r = 0; r < 4; ++r)
        T1[(size_t)(rowb + r) * HIDDEN + col] = fmaxf(acc[i][j][r] + bv, 0.0f);
    }
  }
}

// ---------------- kernel 2: t1 GEMM + QKV GEMM, interleaved 1:3 ----------------
// (blk&3)==3 -> t1 block (256 of 1024); else qkv block (768 of 1024).
// t1's standalone 1-block/CU under-occupancy is cured by co-residency with
// qkv blocks (MFMA+VALU pipes shared across waves of both kinds).
__global__ __launch_bounds__(256) void mega_gemm1(
    const short* __restrict__ qh, const short* __restrict__ ql,
    const short* __restrict__ w1h, const short* __restrict__ w1l,
    const float* __restrict__ inf1_b, float* __restrict__ T1,
    const short* __restrict__ Wq, const short* __restrict__ Wk,
    const short* __restrict__ Wv,
    const float* __restrict__ qb, const float* __restrict__ kb,
    const float* __restrict__ vb,
    short* __restrict__ Qp, short* __restrict__ Kp, short* __restrict__ Vp)
{
  __shared__ __attribute__((aligned(16))) short smem[12288];   // 24 KB union
  int blk = blockIdx.x;
  if ((blk & 3) == 3) {
    int id = blk >> 2;                         // [0,256)
    gemm_t1_body(smem, qh, ql, w1h, w1l, inf1_b, T1,
                 (id & 31) * 128, (id >> 5) * 64);
  } else {
    int id = (blk >> 2) * 3 + (blk & 3);       // [0,768)
    int row0 = (id & 31) * 128;
    int rest = id >> 5;                        // [0,24)
    int mat = rest >> 3, cb = rest & 7;
    const short* B   = (mat == 0) ? Wq : (mat == 1) ? Wk : Wv;
    const float* bia = (mat == 0) ? qb : (mat == 1) ? kb : vb;
    short* out       = (mat == 0) ? Qp : (mat == 1) ? Kp : Vp;
    // q scale folds D^-0.5 * log2(e) (flash softmax runs in exp2 domain)
    float scale      = (mat == 0) ? 0.18033688011112042f : 1.0f;
    gemm128_body<false>(smem, qh, B, bia, (void*)out, row0, cb * 128, scale);
  }
}

// ---------------- kernel 3: head-mask + V-transpose in one launch ----------------
__global__ __launch_bounds__(256) void mid_kernel(
    const float* __restrict__ T1, const float* __restrict__ inf2_w,
    const float* __restrict__ inf2_b, const float* __restrict__ head_sig,
    float* __restrict__ maskbuf,
    const short* __restrict__ Vp, short* __restrict__ VT)
{
  __shared__ __attribute__((aligned(16))) float fsm[16*HIDDEN + 16*SIGD + 16*NHEAD];
  int blk = blockIdx.x;
  const int tid = threadIdx.x;
  if (blk < 256) {
    // ---- head mask: t2 = t1 @ inf2_w^T + b ; s = t2 @ head_sig^T ; top-12 ----
    float (*t1s)[HIDDEN] = (float(*)[HIDDEN])fsm;
    float (*t2s)[SIGD]   = (float(*)[SIGD])(fsm + 16*HIDDEN);
    float (*ss)[NHEAD]   = (float(*)[NHEAD])(fsm + 16*HIDDEN + 16*SIGD);
    const int tok0 = blk * 16;
    {
      int row = tid >> 4, c0 = (tid & 15) * 32;
      const float* src = T1 + (size_t)(tok0 + row) * HIDDEN + c0;
      #pragma unroll
      for (int u = 0; u < 8; ++u)
        *(float4*)&t1s[row][c0 + u*4] = *(const float4*)(src + u*4);
    }
    __syncthreads();
    #pragma unroll
    for (int it = 0; it < 4; ++it) {
      int idx = tid + it * 256;
      int tok = idx >> 6, j = idx & 63;
      const float4* w4 = (const float4*)(inf2_w + (size_t)j * HIDDEN);
      const float4* t4 = (const float4*)(&t1s[tok][0]);
      float a = inf2_b[j];
      for (int k = 0; k < HIDDEN/4; ++k) {
        float4 wv = w4[k], tv = t4[k];
        a += tv.x*wv.x + tv.y*wv.y + tv.z*wv.z + tv.w*wv.w;
      }
      t2s[tok][j] = a;
    }
    __syncthreads();
    {
      int tok = tid >> 4, h = tid & 15;
      float a = 0.f;
      for (int d = 0; d < SIGD; ++d) a += t2s[tok][d] * head_sig[h*SIGD + d];
      ss[tok][h] = a;
    }
    __syncthreads();
    {
      int tok = tid >> 4, h = tid & 15;
      float sv = ss[tok][h];
      int cnt = 0;
      #pragma unroll
      for (int j = 0; j < NHEAD; ++j) cnt += (ss[tok][j] > sv) ? 1 : 0;
      int gt = tok0 + tok;
      int s = gt >> 1, b = gt & 1;             // token row = s*B + b
      maskbuf[((size_t)(b*NHEAD + h)) * S_LEN + s] = (cnt < KEEP) ? 1.0f : 0.0f;
    }
  } else {
    // ---- V transpose: Vp (token-major) -> VT[(b*16+h)*64+d][S_LEN] ----
    short (*tile)[72] = (short(*)[72])fsm;
    int t = blk - 256;                          // [0,1024)
    const int s0 = (t & 31) * 64, e0 = ((t >> 5) & 15) * 64, b = t >> 9;
    {
      int sr = tid >> 2, ec = (tid & 3) * 16;
      const short* src = Vp + (size_t)(s0 + sr) * 2048 + b * 1024 + e0 + ec;
      *(uint4*)&tile[sr][ec]     = *(const uint4*)src;
      *(uint4*)&tile[sr][ec + 8] = *(const uint4*)(src + 8);
    }
    __syncthreads();
    {
      int er = tid >> 2, sc = (tid & 3) * 16;
      unsigned pack[8];
      #pragma unroll
      for (int u = 0; u < 8; ++u) {
        unsigned lo = (unsigned short)tile[sc + 2*u][er];
        unsigned hi = (unsigned short)tile[sc + 2*u + 1][er];
        pack[u] = lo | (hi << 16);
      }
      short* dst = VT + (size_t)(b * 1024 + e0 + er) * 2048 + s0 + sc;
      *(uint4*)(dst)     = *(uint4*)&pack[0];
      *(uint4*)(dst + 8) = *(uint4*)&pack[4];
    }
  }
}

// ---------------- kernel 4: flash attention (exp2 domain) ----------------
// v2: KV-tile 64 (was 128), LDS 53KB -> 25.5KB => 5-6 blocks/CU (was 3) and
// zero grid-tail (1024 blocks all co-resident). Next K/V tile prefetched into
// registers and written to LDS after the barrier (T14 async-STAGE split).
// All LDS strides 68 shorts (word-stride 34 == 2 mod 32: halves read-side
// bank aliasing vs 72/136; Ps scalar writes become conflict-free).
__global__ __launch_bounds__(256) void flash_attn(
    short* QpOg, const short* __restrict__ Kp, const short* __restrict__ VT,
    const float* __restrict__ maskbuf)
{
  __shared__ __attribute__((aligned(16))) short Ks[64][68];    // 8704 B
  __shared__ __attribute__((aligned(16))) short Vt[64][68];    // 8704 B (rows=d, cols=kv)
  __shared__ __attribute__((aligned(16))) short uni[4352];     // Qstage 64x68 | Ps 4x16x68
  const int bh = blockIdx.x;
  const int b = bh >> 4, h = bh & 15;
  const int q0 = blockIdx.y * 64;
  const int tid = threadIdx.x;
  const int wave = tid >> 6, lane = tid & 63;
  const int quad = lane >> 4, l16 = lane & 15;
  const size_t colbase = (size_t)b * EDIM + h * DHEAD;
  const size_t rstride = (size_t)BATCH * EDIM;   // 2048

  const int r4 = tid >> 2, c16 = (tid & 3) * 16;
  const short* gK = Kp + (size_t)r4 * rstride + colbase + c16;          // +kv0*rstride per tile
  const short* gV = VT + (size_t)(bh * 64 + r4) * S_LEN + c16;         // +kv0 per tile

  {  // stage Q into uni, read fragments to regs
    const short* src = QpOg + (size_t)(q0 + r4) * rstride + colbase + c16;
    *(uint4*)&uni[r4*68 + c16]     = *(const uint4*)src;
    *(uint4*)&uni[r4*68 + c16 + 8] = *(const uint4*)(src + 8);
  }
  __syncthreads();
  bf16x8 aq0 = *(const bf16x8*)&uni[(wave*16 + l16)*68 + quad*8];
  bf16x8 aq1 = *(const bf16x8*)&uni[(wave*16 + l16)*68 + 32 + quad*8];
  short* Psw = &uni[wave * 1088];        // per-wave 16 x 68

  // prefetch tile 0 into registers
  uint4 kr0 = *(const uint4*)(gK);      uint4 kr1 = *(const uint4*)(gK + 8);
  uint4 vr0 = *(const uint4*)(gV);      uint4 vr1 = *(const uint4*)(gV + 8);

  float m_i[4], l_i[4];
  f32x4 oacc[4];
  #pragma unroll
  for (int r = 0; r < 4; ++r) { m_i[r] = -1e30f; l_i[r] = 0.f; }
  #pragma unroll
  for (int dt = 0; dt < 4; ++dt) oacc[dt] = f32x4{0.f, 0.f, 0.f, 0.f};

  for (int kv0 = 0; kv0 < S_LEN; kv0 += 64) {
    __syncthreads();              // prev tile's LDS reads (and Q reads) complete
    *(uint4*)&Ks[r4][c16]     = kr0;
    *(uint4*)&Ks[r4][c16 + 8] = kr1;
    *(uint4*)&Vt[r4][c16]     = vr0;
    *(uint4*)&Vt[r4][c16 + 8] = vr1;
    __syncthreads();
    if (kv0 + 64 < S_LEN) {       // issue next-tile loads; drain under compute
      const short* nK = gK + (size_t)(kv0 + 64) * rstride;
      const short* nV = gV + (kv0 + 64);
      kr0 = *(const uint4*)nK;  kr1 = *(const uint4*)(nK + 8);
      vr0 = *(const uint4*)nV;  vr1 = *(const uint4*)(nV + 8);
    }
    f32x4 sacc[4];
    #pragma unroll
    for (int c = 0; c < 4; ++c) sacc[c] = f32x4{0.f, 0.f, 0.f, 0.f};
    __builtin_amdgcn_s_setprio(1);
    #pragma unroll
    for (int c = 0; c < 4; ++c) {
      bf16x8 b0 = *(const bf16x8*)&Ks[c*16 + l16][quad*8];
      bf16x8 b1 = *(const bf16x8*)&Ks[c*16 + l16][32 + quad*8];
      sacc[c] = __builtin_amdgcn_mfma_f32_16x16x32_bf16(aq0, b0, sacc[c], 0, 0, 0);
      sacc[c] = __builtin_amdgcn_mfma_f32_16x16x32_bf16(aq1, b1, sacc[c], 0, 0, 0);
    }
    __builtin_amdgcn_s_setprio(0);
    #pragma unroll
    for (int r = 0; r < 4; ++r) {
      float vmax = fmaxf(fmaxf(sacc[0][r], sacc[1][r]),
                         fmaxf(sacc[2][r], sacc[3][r]));
      vmax = row_max16(vmax);
      float mnew = fmaxf(m_i[r], vmax);
      float alpha = fexp2(m_i[r] - mnew);
      float rsum = 0.f;
      short* prow = &Psw[(quad*4 + r)*68 + l16];
      #pragma unroll
      for (int p = 0; p < 2; ++p) {
        float ea = fexp2(sacc[2*p][r]   - mnew);
        float eb = fexp2(sacc[2*p+1][r] - mnew);
        unsigned pk = __builtin_amdgcn_perm(
            __builtin_bit_cast(unsigned, eb),
            __builtin_bit_cast(unsigned, ea), 0x07060302u);
        prow[(2*p)*16]     = (short)(pk & 0xffffu);
        prow[(2*p + 1)*16] = (short)(pk >> 16);
        rsum += ea + eb;
      }
      rsum = row_sum16(rsum);
      l_i[r] = l_i[r] * alpha + rsum;
      m_i[r] = mnew;
      #pragma unroll
      for (int dt = 0; dt < 4; ++dt) oacc[dt][r] *= alpha;
    }
    asm volatile("s_waitcnt lgkmcnt(0)" ::: "memory");   // Ps visible (same wave)
    __builtin_amdgcn_s_setprio(1);
    #pragma unroll
    for (int ks = 0; ks < 2; ++ks) {
      bf16x8 ap = *(const bf16x8*)&Psw[l16*68 + ks*32 + quad*8];
      #pragma unroll
      for (int dt = 0; dt < 4; ++dt) {
        bf16x8 bb = *(const bf16x8*)&Vt[dt*16 + l16][ks*32 + quad*8];
        oacc[dt] = __builtin_amdgcn_mfma_f32_16x16x32_bf16(ap, bb, oacc[dt], 0, 0, 0);
      }
    }
    __builtin_amdgcn_s_setprio(0);
  }
  #pragma unroll
  for (int r = 0; r < 4; ++r) {
    int s = q0 + wave*16 + quad*4 + r;
    float mk = maskbuf[((size_t)(b*NHEAD + h)) * S_LEN + s];
    float scale = mk / l_i[r];
    short* dst = QpOg + (size_t)s * rstride + colbase;
    #pragma unroll
    for (int dt = 0; dt < 4; ++dt)
      dst[dt*16 + l16] = f2bf(oacc[dt][r] * scale);
  }
}

// ---------------- kernel 5: out projection ----------------
__global__ __launch_bounds__(256) void gemm_out(
    const short* __restrict__ A, const short* __restrict__ W,
    const float* __restrict__ bias, float* __restrict__ out)
{
  __shared__ __attribute__((aligned(16))) short smem[8192];
  gemm128_body<true>(smem, A, W, bias, (void*)out,
                     blockIdx.x * 128, blockIdx.y * 128, 1.0f);
}

extern "C" void kernel_launch(void* const* d_in, const int* in_sizes, int n_in,
                              void* d_out, int out_size, void* d_ws, size_t ws_size,
                              hipStream_t stream)
{
  const float* query   = (const float*)d_in[0];
  const float* q_w     = (const float*)d_in[1];
  const float* q_b     = (const float*)d_in[2];
  const float* k_w     = (const float*)d_in[3];
  const float* k_b     = (const float*)d_in[4];
  const float* v_w     = (const float*)d_in[5];
  const float* v_b     = (const float*)d_in[6];
  const float* out_w   = (const float*)d_in[7];
  const float* out_b   = (const float*)d_in[8];
  const float* inf1_w  = (const float*)d_in[9];
  const float* inf1_b  = (const float*)d_in[10];
  const float* inf2_w  = (const float*)d_in[11];
  const float* inf2_b  = (const float*)d_in[12];
  const float* head_sig= (const float*)d_in[13];

  // ws (>= 42 MB, proven by R2's 42 MB footprint):
  //  [0,8)  qh   -> VT after mid_kernel (qh dead post mega_gemm1)
  //  [8,16) ql   -> maskbuf (256 KB) after mega_gemm1
  //  [16,24) Qp  -> gated O (flash in-place)
  //  [24,32) Kp
  //  [32,40) Vp  (dead after mid_kernel)
  //  [40,42) Wo  (written by cvt_all, read by gemm_out; untouched between)
  char* ws = (char*)d_ws;
  short* qh      = (short*)(ws);
  short* VTb     = (short*)(ws);
  short* ql      = (short*)(ws + (size_t)( 8u<<20));
  float* maskbuf = (float*)(ws + (size_t)( 8u<<20));
  short* Qp      = (short*)(ws + (size_t)(16u<<20));
  short* Kp      = (short*)(ws + (size_t)(24u<<20));
  short* Vp      = (short*)(ws + (size_t)(32u<<20));
  short* Wo      = (short*)(ws + (size_t)(40u<<20));
  // d_out (16 MB fp32) as scratch until gemm_out overwrites all of it:
  //  [0,8) T1 fp32 ; [8,9) w1h ; [9,10) w1l ; [10,12) Wq ; [12,14) Wk ; [14,16) Wv
  char* ob = (char*)d_out;
  float* T1  = (float*)(ob);
  short* w1h = (short*)(ob + (size_t)( 8u<<20));
  short* w1l = (short*)(ob + (size_t)( 9u<<20));
  short* Wq  = (short*)(ob + (size_t)(10u<<20));
  short* Wk  = (short*)(ob + (size_t)(12u<<20));
  short* Wv  = (short*)(ob + (size_t)(14u<<20));
  float* out = (float*)d_out;

  dim3 blk(256);
  cvt_all<<<dim3(8704), blk, 0, stream>>>(query, inf1_w, q_w, k_w, v_w, out_w,
                                          qh, ql, w1h, w1l, Wq, Wk, Wv, Wo);
  mega_gemm1<<<dim3(1024), blk, 0, stream>>>(qh, ql, w1h, w1l, inf1_b, T1,
                                             Wq, Wk, Wv, q_b, k_b, v_b, Qp, Kp, Vp);
  mid_kernel<<<dim3(1280), blk, 0, stream>>>(T1, inf2_w, inf2_b, head_sig, maskbuf,
                                             Vp, VTb);
  flash_attn<<<dim3(32, 32), blk, 0, stream>>>(Qp, Kp, VTb, maskbuf);
  gemm_out<<<dim3(32, 8), blk, 0, stream>>>(Qp, Wo, out_b, out);
}